// Round 13
// baseline (347.220 us; speedup 1.0000x reference)
//
#include <hip/hip_runtime.h>
#include <hip/hip_bf16.h>

// GCN: out = relu(gcnconv(relu(gcnconv(x,W1,b1)), W2, b2)) @ Wfc + bfc
// N=50000, E=800000, F0=100, F1=256, F2=128.
// Round 22: r21 accounting shows ~160 us in the never-profiled CSR chain +
// dispatch gaps (profiled kernels: gemm12 62.5, pulls <62 each). Bundle:
// (1) scale_x fused into scan1 (dinv via LDS), (2) deg_count/csr_fill int4
// edge reads (4 edges/thread), (3) s_setprio(1) around gemm12 MFMA clusters
// (stage-1 is barrier-free drifting waves — the T5-favorable regime).
// gemm12/pulls otherwise unchanged from r21 (measured best composition).
// Numerics: split-fp16 3-term MFMA (ah*bh+ah*bl+al*bh, fp32 acc), absmax
// 4.9e-4 passing since r15.

#define F0 100
#define F1 256
#define F2 128

typedef _Float16 f16x4 __attribute__((ext_vector_type(4)));
typedef _Float16 f16x8 __attribute__((ext_vector_type(8)));
typedef float f32x4 __attribute__((ext_vector_type(4)));

// ---------------- CSR construction ----------------

// 4 edges per thread, vectorized int4 read of dst
__global__ void deg_count_i(const int* __restrict__ dst, int* deg, int e) {
    int i = blockIdx.x * blockDim.x + threadIdx.x;
    int base = i * 4;
    if (base + 3 < e) {
        int4 d = *(const int4*)(dst + base);
        atomicAdd(deg + d.x, 1);
        atomicAdd(deg + d.y, 1);
        atomicAdd(deg + d.z, 1);
        atomicAdd(deg + d.w, 1);
    } else {
        for (int k = base; k < e; ++k) atomicAdd(deg + dst[k], 1);
    }
}

// per-block exclusive scan of deg + block sums; emits dinv = rsqrt(deg+1)
// AND scales this block's 256 rows of x into xs (fused former scale_x).
__global__ __launch_bounds__(256) void scan1_scale(
        const int* __restrict__ deg, int* __restrict__ excl,
        int* __restrict__ bsum, float* __restrict__ dinv,
        const float4* __restrict__ x4, float4* __restrict__ xs4, int n) {
    __shared__ int wsum[4];
    __shared__ float sd[256];
    int i = blockIdx.x * 256 + threadIdx.x;
    int lane = threadIdx.x & 63, wid = threadIdx.x >> 6;
    int v = (i < n) ? deg[i] : 0;
    float dv = rsqrtf((float)(v + 1));
    sd[threadIdx.x] = dv;
    if (i < n) dinv[i] = dv;
    int s = v;
#pragma unroll
    for (int off = 1; off < 64; off <<= 1) {
        int t = __shfl_up(s, off, 64);
        if (lane >= off) s += t;
    }
    if (lane == 63) wsum[wid] = s;
    __syncthreads();
    int add = 0;
    for (int w = 0; w < wid; w++) add += wsum[w];
    if (i < n) excl[i] = add + s - v;
    if (threadIdx.x == 255) bsum[blockIdx.x] = add + s;

    // fused xs = dinv[row] * x : this block's 256 rows (25 float4 each)
    int r0b = blockIdx.x * 256;
    for (int j = threadIdx.x; j < 256 * 25; j += 256) {
        int row = j / 25, q = j - row * 25;
        int gr = r0b + row;
        if (gr < n) {
            float d = sd[row];
            float4 t = x4[(size_t)gr * 25 + q];
            t.x *= d; t.y *= d; t.z *= d; t.w *= d;
            xs4[(size_t)gr * 25 + q] = t;
        }
    }
}

__global__ __launch_bounds__(256) void scan2(int* __restrict__ bsum, int nb,
                                             int* __restrict__ rowptr, int n) {
    __shared__ int wsum[4];
    int lane = threadIdx.x & 63, wid = threadIdx.x >> 6;
    int v = (threadIdx.x < nb) ? bsum[threadIdx.x] : 0;
    int s = v;
#pragma unroll
    for (int off = 1; off < 64; off <<= 1) {
        int t = __shfl_up(s, off, 64);
        if (lane >= off) s += t;
    }
    if (lane == 63) wsum[wid] = s;
    __syncthreads();
    int add = 0;
    for (int w = 0; w < wid; w++) add += wsum[w];
    if (threadIdx.x < nb) bsum[threadIdx.x] = add + s - v;
    if (threadIdx.x == 255) rowptr[n] = add + s;
}

__global__ void scan3(const int* __restrict__ excl, const int* __restrict__ bsum,
                      int* __restrict__ rowptr, int* __restrict__ cursor, int n) {
    int i = blockIdx.x * 256 + threadIdx.x;
    if (i < n) {
        int r = excl[i] + bsum[blockIdx.x];
        rowptr[i] = r;
        cursor[i] = r;
    }
}

// 4 edges per thread, vectorized int4 reads of src+dst
__global__ void csr_fill(const int* __restrict__ src, const int* __restrict__ dst,
                         int* cursor, int* __restrict__ csr, int e) {
    int i = blockIdx.x * blockDim.x + threadIdx.x;
    int base = i * 4;
    if (base + 3 < e) {
        int4 d = *(const int4*)(dst + base);
        int4 sc = *(const int4*)(src + base);
        csr[atomicAdd(cursor + d.x, 1)] = sc.x;
        csr[atomicAdd(cursor + d.y, 1)] = sc.y;
        csr[atomicAdd(cursor + d.z, 1)] = sc.z;
        csr[atomicAdd(cursor + d.w, 1)] = sc.w;
    } else {
        for (int k = base; k < e; ++k)
            csr[atomicAdd(cursor + dst[k], 1)] = src[k];
    }
}

// W1t_h/l: [256][128] = W1^T zero-padded K 100->128, split fp16 hi/lo.
// W2t_h/l: [128][256] = W2^T, split fp16 hi/lo.
__global__ void wprep(const float* __restrict__ W1, const float* __restrict__ W2,
                      _Float16* __restrict__ W1h, _Float16* __restrict__ W1l,
                      _Float16* __restrict__ W2h, _Float16* __restrict__ W2l) {
    int i = blockIdx.x * 256 + threadIdx.x;
    if (i < 256 * 128) {
        int c = i >> 7, k = i & 127;
        float v = (k < F0) ? W1[(size_t)k * F1 + c] : 0.f;
        _Float16 h = (_Float16)v;
        W1h[i] = h;
        W1l[i] = (_Float16)(v - (float)h);
    } else if (i < 256 * 128 + 128 * 256) {
        int j = i - 256 * 128;
        int c = j >> 8, k = j & 255;
        float v = W2[(size_t)k * F2 + c];
        _Float16 h = (_Float16)v;
        W2h[j] = h;
        W2l[j] = (_Float16)(v - (float)h);
    }
}

// ---------------- layer-1 pull aggregation -> split-fp16 aggX -------------

__global__ __launch_bounds__(256) void pull_f100(
        const float* __restrict__ xs, const int* __restrict__ rowptr,
        const int* __restrict__ csr, const float* __restrict__ dinv,
        _Float16* __restrict__ aggh, _Float16* __restrict__ aggl, int n) {
    int wave = threadIdx.x >> 6, lane = threadIdx.x & 63;
    int v = blockIdx.x * 4 + wave;
    if (v >= n) return;
    int beg = rowptr[v], end = rowptr[v + 1];
    float dv = dinv[v];
    int half = lane >> 5, q = lane & 31;
    bool act = q < 25;
    float4 acc = {0.f, 0.f, 0.f, 0.f};
    if (half == 0 && act) acc = ((const float4*)(xs + (size_t)v * F0))[q];  // self

    for (int base = beg; base < end; base += 64) {
        int cnt = min(64, end - base);
        int sidx = (lane < cnt) ? csr[base + lane] : 0;
        int npf = cnt >> 1;
        int p = 0;
        for (; p + 4 <= npf; p += 4) {
            int s0 = __shfl(sidx, 2 * p + half, 64);
            int s1 = __shfl(sidx, 2 * p + 2 + half, 64);
            int s2 = __shfl(sidx, 2 * p + 4 + half, 64);
            int s3 = __shfl(sidx, 2 * p + 6 + half, 64);
            if (act) {
                float4 r0 = ((const float4*)(xs + (size_t)s0 * F0))[q];
                float4 r1 = ((const float4*)(xs + (size_t)s1 * F0))[q];
                float4 r2 = ((const float4*)(xs + (size_t)s2 * F0))[q];
                float4 r3 = ((const float4*)(xs + (size_t)s3 * F0))[q];
                acc.x += (r0.x + r1.x) + (r2.x + r3.x);
                acc.y += (r0.y + r1.y) + (r2.y + r3.y);
                acc.z += (r0.z + r1.z) + (r2.z + r3.z);
                acc.w += (r0.w + r1.w) + (r2.w + r3.w);
            }
        }
        for (; p < npf; p++) {
            int s0 = __shfl(sidx, 2 * p + half, 64);
            if (act) {
                float4 r0 = ((const float4*)(xs + (size_t)s0 * F0))[q];
                acc.x += r0.x; acc.y += r0.y; acc.z += r0.z; acc.w += r0.w;
            }
        }
        if (cnt & 1) {
            int sl = __shfl(sidx, cnt - 1, 64);
            if (half == 0 && act) {
                float4 r = ((const float4*)(xs + (size_t)sl * F0))[q];
                acc.x += r.x; acc.y += r.y; acc.z += r.z; acc.w += r.w;
            }
        }
    }
    float ox = __shfl_down(acc.x, 32, 64);
    float oy = __shfl_down(acc.y, 32, 64);
    float oz = __shfl_down(acc.z, 32, 64);
    float ow = __shfl_down(acc.w, 32, 64);
    if (half == 0) {
        float4 r = {0.f, 0.f, 0.f, 0.f};
        if (act) {
            r.x = dv * (acc.x + ox);
            r.y = dv * (acc.y + oy);
            r.z = dv * (acc.z + oz);
            r.w = dv * (acc.w + ow);
        }
        f16x4 hh, ll;
        hh[0] = (_Float16)r.x; ll[0] = (_Float16)(r.x - (float)hh[0]);
        hh[1] = (_Float16)r.y; ll[1] = (_Float16)(r.y - (float)hh[1]);
        hh[2] = (_Float16)r.z; ll[2] = (_Float16)(r.z - (float)hh[2]);
        hh[3] = (_Float16)r.w; ll[3] = (_Float16)(r.w - (float)hh[3]);
        *(f16x4*)(aggh + (size_t)v * 128 + 4 * q) = hh;
        *(f16x4*)(aggl + (size_t)v * 128 + 4 * q) = ll;
    }
}

// ---------------- fused GEMM1+GEMM2 (split-fp16 MFMA), r16 structure ------
// 8 waves (512 thr), M-tile 128, grid 391. Stage-1 barrier-free (waves
// drift) -> s_setprio(1) around MFMA clusters (T5-favorable regime).
__global__ __launch_bounds__(512) void gemm12_fused(
        const _Float16* __restrict__ Ah, const _Float16* __restrict__ Al,
        const _Float16* __restrict__ W1h, const _Float16* __restrict__ W1l,
        const _Float16* __restrict__ W2h, const _Float16* __restrict__ W2l,
        const float* __restrict__ b1, const float* __restrict__ dinv,
        float* __restrict__ C, int n) {
    __shared__ _Float16 sAh[128][136], sAl[128][136];   // 68 KB
    int tid = threadIdx.x, lane = tid & 63, wave = tid >> 6;
    int wm = wave >> 2, wn = wave & 3;
    int r0 = blockIdx.x * 128;
    int lr = lane & 15, kg = lane >> 4, ks8 = kg * 8;

    // ---- stage 1 ----
    f32x4 acc1[4][4] = {};
    int arow[4];
#pragma unroll
    for (int i = 0; i < 4; ++i) arow[i] = min(r0 + wm * 64 + i * 16 + lr, n - 1);

#pragma unroll
    for (int k0 = 0; k0 < 128; k0 += 32) {
        f16x8 a_h[4], a_l[4], b_h[4], b_l[4];
#pragma unroll
        for (int i = 0; i < 4; ++i) {
            a_h[i] = *(const f16x8*)(Ah + (size_t)arow[i] * 128 + k0 + ks8);
            a_l[i] = *(const f16x8*)(Al + (size_t)arow[i] * 128 + k0 + ks8);
        }
#pragma unroll
        for (int j = 0; j < 4; ++j) {
            int col = wn * 64 + j * 16 + lr;
            b_h[j] = *(const f16x8*)(W1h + (size_t)col * 128 + k0 + ks8);
            b_l[j] = *(const f16x8*)(W1l + (size_t)col * 128 + k0 + ks8);
        }
        __builtin_amdgcn_s_setprio(1);
#pragma unroll
        for (int i = 0; i < 4; ++i)
#pragma unroll
            for (int j = 0; j < 4; ++j) {
                acc1[i][j] = __builtin_amdgcn_mfma_f32_16x16x32_f16(a_l[i], b_h[j], acc1[i][j], 0, 0, 0);
                acc1[i][j] = __builtin_amdgcn_mfma_f32_16x16x32_f16(a_h[i], b_l[j], acc1[i][j], 0, 0, 0);
                acc1[i][j] = __builtin_amdgcn_mfma_f32_16x16x32_f16(a_h[i], b_h[j], acc1[i][j], 0, 0, 0);
            }
        __builtin_amdgcn_s_setprio(0);
    }
    // bias + relu
#pragma unroll
    for (int j = 0; j < 4; ++j) {
        float bv = b1[wn * 64 + j * 16 + lr];
#pragma unroll
        for (int i = 0; i < 4; ++i)
#pragma unroll
            for (int r = 0; r < 4; ++r)
                acc1[i][j][r] = fmaxf(acc1[i][j][r] + bv, 0.f);
    }

    // ---- stage 2: two 128-mid-col halves through LDS ----
    f32x4 acc2[4][2] = {};
#pragma unroll
    for (int half = 0; half < 2; ++half) {
        if (half) __syncthreads();          // all reads of prev half done
        if ((wn >> 1) == half) {
            int cb = (wn & 1) * 64;
#pragma unroll
            for (int i = 0; i < 4; ++i)
#pragma unroll
                for (int j = 0; j < 4; ++j)
#pragma unroll
                    for (int r = 0; r < 4; ++r) {
                        int row = wm * 64 + i * 16 + kg * 4 + r;
                        int col = cb + j * 16 + lr;
                        float v = acc1[i][j][r];
                        _Float16 h = (_Float16)v;
                        sAh[row][col] = h;
                        sAl[row][col] = (_Float16)(v - (float)h);
                    }
        }
        __syncthreads();
#pragma unroll
        for (int k0 = 0; k0 < 128; k0 += 32) {
            f16x8 a_h[4], a_l[4], b_h[2], b_l[2];
#pragma unroll
            for (int i = 0; i < 4; ++i) {
                a_h[i] = *(const f16x8*)&sAh[wm * 64 + i * 16 + lr][k0 + ks8];
                a_l[i] = *(const f16x8*)&sAl[wm * 64 + i * 16 + lr][k0 + ks8];
            }
#pragma unroll
            for (int j = 0; j < 2; ++j) {
                int col = wn * 32 + j * 16 + lr;
                int kk = half * 128 + k0 + ks8;
                b_h[j] = *(const f16x8*)(W2h + (size_t)col * 256 + kk);
                b_l[j] = *(const f16x8*)(W2l + (size_t)col * 256 + kk);
            }
            __builtin_amdgcn_s_setprio(1);
#pragma unroll
            for (int i = 0; i < 4; ++i)
#pragma unroll
                for (int j = 0; j < 2; ++j) {
                    acc2[i][j] = __builtin_amdgcn_mfma_f32_16x16x32_f16(a_l[i], b_h[j], acc2[i][j], 0, 0, 0);
                    acc2[i][j] = __builtin_amdgcn_mfma_f32_16x16x32_f16(a_h[i], b_l[j], acc2[i][j], 0, 0, 0);
                    acc2[i][j] = __builtin_amdgcn_mfma_f32_16x16x32_f16(a_h[i], b_h[j], acc2[i][j], 0, 0, 0);
                }
            __builtin_amdgcn_s_setprio(0);
        }
    }

    // ---- epilogue: dinv scale, ROW-MAJOR h2 write ----
#pragma unroll
    for (int i = 0; i < 4; ++i)
#pragma unroll
        for (int r = 0; r < 4; ++r) {
            int gr = r0 + wm * 64 + i * 16 + kg * 4 + r;
            if (gr < n) {
                float d = dinv[gr];
#pragma unroll
                for (int j = 0; j < 2; ++j) {
                    int col = wn * 32 + j * 16 + lr;
                    C[(size_t)gr * F2 + col] = acc2[i][j][r] * d;
                }
            }
        }
}

// ---------------- layer-2 fused pull (r10 unchunked) ----------------
__global__ __launch_bounds__(256) void pull_f128_fused(
        const float* __restrict__ h2s, const int* __restrict__ rowptr,
        const int* __restrict__ csr, const float* __restrict__ dinv,
        const float* __restrict__ b2, const float* __restrict__ Wfc,
        const float* __restrict__ bfc, float* __restrict__ out, int n) {
    int wave = threadIdx.x >> 6, lane = threadIdx.x & 63;
    int v = blockIdx.x * 4 + wave;
    if (v >= n) return;
    int beg = rowptr[v], end = rowptr[v + 1];
    float dv = dinv[v];
    int half = lane >> 5, q = lane & 31;
    float4 acc = {0.f, 0.f, 0.f, 0.f};
    if (half == 0) acc = ((const float4*)(h2s + (size_t)v * F2))[q];  // self

    for (int base = beg; base < end; base += 64) {
        int cnt = min(64, end - base);
        int sidx = (lane < cnt) ? csr[base + lane] : 0;
        int npf = cnt >> 1;
        int p = 0;
        for (; p + 4 <= npf; p += 4) {
            int s0 = __shfl(sidx, 2 * p + half, 64);
            int s1 = __shfl(sidx, 2 * p + 2 + half, 64);
            int s2 = __shfl(sidx, 2 * p + 4 + half, 64);
            int s3 = __shfl(sidx, 2 * p + 6 + half, 64);
            float4 r0 = ((const float4*)(h2s + (size_t)s0 * F2))[q];
            float4 r1 = ((const float4*)(h2s + (size_t)s1 * F2))[q];
            float4 r2 = ((const float4*)(h2s + (size_t)s2 * F2))[q];
            float4 r3 = ((const float4*)(h2s + (size_t)s3 * F2))[q];
            acc.x += (r0.x + r1.x) + (r2.x + r3.x);
            acc.y += (r0.y + r1.y) + (r2.y + r3.y);
            acc.z += (r0.z + r1.z) + (r2.z + r3.z);
            acc.w += (r0.w + r1.w) + (r2.w + r3.w);
        }
        for (; p < npf; p++) {
            int s0 = __shfl(sidx, 2 * p + half, 64);
            float4 r0 = ((const float4*)(h2s + (size_t)s0 * F2))[q];
            acc.x += r0.x; acc.y += r0.y; acc.z += r0.z; acc.w += r0.w;
        }
        if (cnt & 1) {
            int sl = __shfl(sidx, cnt - 1, 64);
            if (half == 0) {
                float4 r = ((const float4*)(h2s + (size_t)sl * F2))[q];
                acc.x += r.x; acc.y += r.y; acc.z += r.z; acc.w += r.w;
            }
        }
    }
    float ox = __shfl_down(acc.x, 32, 64);
    float oy = __shfl_down(acc.y, 32, 64);
    float oz = __shfl_down(acc.z, 32, 64);
    float ow = __shfl_down(acc.w, 32, 64);
    if (half == 0) {
        float4 b2v = ((const float4*)b2)[q];
        float4 wv = ((const float4*)Wfc)[q];
        float t0 = dv * (acc.x + ox);
        float t1 = dv * (acc.y + oy);
        float t2 = dv * (acc.z + oz);
        float t3 = dv * (acc.w + ow);
        float part = fmaxf(t0 + b2v.x, 0.f) * wv.x + fmaxf(t1 + b2v.y, 0.f) * wv.y +
                     fmaxf(t2 + b2v.z, 0.f) * wv.z + fmaxf(t3 + b2v.w, 0.f) * wv.w;
        part += __shfl_down(part, 16, 64);
        part += __shfl_down(part, 8, 64);
        part += __shfl_down(part, 4, 64);
        part += __shfl_down(part, 2, 64);
        part += __shfl_down(part, 1, 64);
        if (lane == 0) out[v] = part + bfc[0];
    }
}

// ---------------- launch ----------------

extern "C" void kernel_launch(void* const* d_in, const int* in_sizes, int n_in,
                              void* d_out, int out_size, void* d_ws, size_t ws_size,
                              hipStream_t stream) {
    const float* x   = (const float*)d_in[0];
    const int*   ei  = (const int*)d_in[1];
    const float* W1  = (const float*)d_in[2];
    const float* b1  = (const float*)d_in[3];
    const float* W2  = (const float*)d_in[4];
    const float* b2  = (const float*)d_in[5];
    const float* Wfc = (const float*)d_in[6];
    const float* bfc = (const float*)d_in[7];
    float* out = (float*)d_out;

    const int n = in_sizes[0] / F0;   // 50000
    const int e = in_sizes[1] / 2;    // 800000
    const int* src = ei;
    const int* dst = ei + e;

    // workspace (byte offsets, 256-B aligned regions, lifetime unions)
    char* wsb = (char*)d_ws;
    size_t off = 0;
    auto alloc = [&](size_t bytes) -> void* {
        off = (off + 255) & ~(size_t)255;
        void* r = wsb + off;
        off += bytes;
        return r;
    };
    int* deg    = (int*)alloc((size_t)n * 4);
    int* excl   = (int*)alloc((size_t)n * 4);
    int* bsum   = (int*)alloc(1024);
    int* rowptr = (int*)alloc((size_t)(n + 1) * 4);
    int* cursor = (int*)alloc((size_t)n * 4);
    int* csr    = (int*)alloc((size_t)e * 4);
    float* dinv = (float*)alloc((size_t)n * 4);
    _Float16* W1h = (_Float16*)alloc(256 * 128 * 2);
    _Float16* W1l = (_Float16*)alloc(256 * 128 * 2);
    _Float16* W2h = (_Float16*)alloc(128 * 256 * 2);
    _Float16* W2l = (_Float16*)alloc(128 * 256 * 2);
    // bufA: xs (n*100 f32) THEN h2 (n*128 f32); xs dead before gemm12 writes
    char* bufA = (char*)alloc((size_t)n * 128 * 4);
    float* xs = (float*)bufA;
    float* h2 = (float*)bufA;
    // aggX h/l: alive from pull_f100 through gemm12 — own region
    _Float16* aggh = (_Float16*)alloc((size_t)n * 128 * 2);
    _Float16* aggl = (_Float16*)alloc((size_t)n * 128 * 2);

    const int B = 256;
    const int nb = (n + B - 1) / B;
    const int e4 = (e + 3) / 4;

    hipMemsetAsync(deg, 0, (size_t)n * 4, stream);
    deg_count_i<<<(e4 + B - 1) / B, B, 0, stream>>>(dst, deg, e);
    scan1_scale<<<nb, B, 0, stream>>>(deg, excl, bsum, dinv,
                                      (const float4*)x, (float4*)xs, n);
    wprep<<<256, 256, 0, stream>>>(W1, W2, W1h, W1l, W2h, W2l);
    scan2<<<1, B, 0, stream>>>(bsum, nb, rowptr, n);
    scan3<<<nb, B, 0, stream>>>(excl, bsum, rowptr, cursor, n);
    csr_fill<<<(e4 + B - 1) / B, B, 0, stream>>>(src, dst, cursor, csr, e);

    // layer 1: pull-aggregate xs -> split-fp16 aggX
    pull_f100<<<(n + 3) / 4, 256, 0, stream>>>(xs, rowptr, csr, dinv, aggh, aggl, n);
    // fused GEMM1+GEMM2 -> row-major pre-scaled h2 (overwrites dead xs region)
    gemm12_fused<<<(n + 127) / 128, 512, 0, stream>>>(aggh, aggl, W1h, W1l,
                                                      W2h, W2l, b1, dinv, h2, n);
    // layer-2 fused pull + bias + relu + FC
    pull_f128_fused<<<(n + 3) / 4, 256, 0, stream>>>(h2, rowptr, csr, dinv,
                                                     b2, Wfc, bfc, out, n);
}

// Round 14
// 343.744 us; speedup vs baseline: 1.0101x; 1.0101x over previous
//
#include <hip/hip_runtime.h>
#include <hip/hip_bf16.h>

// GCN: out = relu(gcnconv(relu(gcnconv(x,W1,b1)), W2, b2)) @ Wfc + bfc
// N=50000, E=800000, F0=100, F1=256, F2=128.
// Round 23: unbundle r22 (+10.6 regression). r22's profile finally exposed
// csr_fill: 62-65 us, VALU 0.2%, WRITE 53 MB = 800k x 64B write-allocate —
// scatter-bound; int4 4-edges/thread only shrank the latency-hiding wave
// pool (same mistake class as r11). Revert deg_count/csr_fill to
// 1-edge/thread, revert gemm12 setprio (T5 null in barrier-synced GEMM).
// Keep ONLY scan1_scale fusion as the single variable vs r21's proven
// 336.6 us composition. Numerics unchanged: split-fp16 3-term MFMA,
// absmax 4.9e-4 passing since r15.

#define F0 100
#define F1 256
#define F2 128

typedef _Float16 f16x4 __attribute__((ext_vector_type(4)));
typedef _Float16 f16x8 __attribute__((ext_vector_type(8)));
typedef float f32x4 __attribute__((ext_vector_type(4)));

// ---------------- CSR construction ----------------

__global__ void deg_count_i(const int* __restrict__ dst, int* deg, int e) {
    int i = blockIdx.x * blockDim.x + threadIdx.x;
    if (i < e) atomicAdd(deg + dst[i], 1);
}

// per-block exclusive scan of deg + block sums; emits dinv = rsqrt(deg+1)
// AND scales this block's 256 rows of x into xs (fused former scale_x).
__global__ __launch_bounds__(256) void scan1_scale(
        const int* __restrict__ deg, int* __restrict__ excl,
        int* __restrict__ bsum, float* __restrict__ dinv,
        const float4* __restrict__ x4, float4* __restrict__ xs4, int n) {
    __shared__ int wsum[4];
    __shared__ float sd[256];
    int i = blockIdx.x * 256 + threadIdx.x;
    int lane = threadIdx.x & 63, wid = threadIdx.x >> 6;
    int v = (i < n) ? deg[i] : 0;
    float dv = rsqrtf((float)(v + 1));
    sd[threadIdx.x] = dv;
    if (i < n) dinv[i] = dv;
    int s = v;
#pragma unroll
    for (int off = 1; off < 64; off <<= 1) {
        int t = __shfl_up(s, off, 64);
        if (lane >= off) s += t;
    }
    if (lane == 63) wsum[wid] = s;
    __syncthreads();
    int add = 0;
    for (int w = 0; w < wid; w++) add += wsum[w];
    if (i < n) excl[i] = add + s - v;
    if (threadIdx.x == 255) bsum[blockIdx.x] = add + s;

    // fused xs = dinv[row] * x : this block's 256 rows (25 float4 each)
    int r0b = blockIdx.x * 256;
    for (int j = threadIdx.x; j < 256 * 25; j += 256) {
        int row = j / 25, q = j - row * 25;
        int gr = r0b + row;
        if (gr < n) {
            float d = sd[row];
            float4 t = x4[(size_t)gr * 25 + q];
            t.x *= d; t.y *= d; t.z *= d; t.w *= d;
            xs4[(size_t)gr * 25 + q] = t;
        }
    }
}

__global__ __launch_bounds__(256) void scan2(int* __restrict__ bsum, int nb,
                                             int* __restrict__ rowptr, int n) {
    __shared__ int wsum[4];
    int lane = threadIdx.x & 63, wid = threadIdx.x >> 6;
    int v = (threadIdx.x < nb) ? bsum[threadIdx.x] : 0;
    int s = v;
#pragma unroll
    for (int off = 1; off < 64; off <<= 1) {
        int t = __shfl_up(s, off, 64);
        if (lane >= off) s += t;
    }
    if (lane == 63) wsum[wid] = s;
    __syncthreads();
    int add = 0;
    for (int w = 0; w < wid; w++) add += wsum[w];
    if (threadIdx.x < nb) bsum[threadIdx.x] = add + s - v;
    if (threadIdx.x == 255) rowptr[n] = add + s;
}

__global__ void scan3(const int* __restrict__ excl, const int* __restrict__ bsum,
                      int* __restrict__ rowptr, int* __restrict__ cursor, int n) {
    int i = blockIdx.x * 256 + threadIdx.x;
    if (i < n) {
        int r = excl[i] + bsum[blockIdx.x];
        rowptr[i] = r;
        cursor[i] = r;
    }
}

__global__ void csr_fill(const int* __restrict__ src, const int* __restrict__ dst,
                         int* cursor, int* __restrict__ csr, int e) {
    int i = blockIdx.x * blockDim.x + threadIdx.x;
    if (i < e) {
        int pos = atomicAdd(cursor + dst[i], 1);
        csr[pos] = src[i];
    }
}

// W1t_h/l: [256][128] = W1^T zero-padded K 100->128, split fp16 hi/lo.
// W2t_h/l: [128][256] = W2^T, split fp16 hi/lo.
__global__ void wprep(const float* __restrict__ W1, const float* __restrict__ W2,
                      _Float16* __restrict__ W1h, _Float16* __restrict__ W1l,
                      _Float16* __restrict__ W2h, _Float16* __restrict__ W2l) {
    int i = blockIdx.x * 256 + threadIdx.x;
    if (i < 256 * 128) {
        int c = i >> 7, k = i & 127;
        float v = (k < F0) ? W1[(size_t)k * F1 + c] : 0.f;
        _Float16 h = (_Float16)v;
        W1h[i] = h;
        W1l[i] = (_Float16)(v - (float)h);
    } else if (i < 256 * 128 + 128 * 256) {
        int j = i - 256 * 128;
        int c = j >> 8, k = j & 255;
        float v = W2[(size_t)k * F2 + c];
        _Float16 h = (_Float16)v;
        W2h[j] = h;
        W2l[j] = (_Float16)(v - (float)h);
    }
}

// ---------------- layer-1 pull aggregation -> split-fp16 aggX -------------

__global__ __launch_bounds__(256) void pull_f100(
        const float* __restrict__ xs, const int* __restrict__ rowptr,
        const int* __restrict__ csr, const float* __restrict__ dinv,
        _Float16* __restrict__ aggh, _Float16* __restrict__ aggl, int n) {
    int wave = threadIdx.x >> 6, lane = threadIdx.x & 63;
    int v = blockIdx.x * 4 + wave;
    if (v >= n) return;
    int beg = rowptr[v], end = rowptr[v + 1];
    float dv = dinv[v];
    int half = lane >> 5, q = lane & 31;
    bool act = q < 25;
    float4 acc = {0.f, 0.f, 0.f, 0.f};
    if (half == 0 && act) acc = ((const float4*)(xs + (size_t)v * F0))[q];  // self

    for (int base = beg; base < end; base += 64) {
        int cnt = min(64, end - base);
        int sidx = (lane < cnt) ? csr[base + lane] : 0;
        int npf = cnt >> 1;
        int p = 0;
        for (; p + 4 <= npf; p += 4) {
            int s0 = __shfl(sidx, 2 * p + half, 64);
            int s1 = __shfl(sidx, 2 * p + 2 + half, 64);
            int s2 = __shfl(sidx, 2 * p + 4 + half, 64);
            int s3 = __shfl(sidx, 2 * p + 6 + half, 64);
            if (act) {
                float4 r0 = ((const float4*)(xs + (size_t)s0 * F0))[q];
                float4 r1 = ((const float4*)(xs + (size_t)s1 * F0))[q];
                float4 r2 = ((const float4*)(xs + (size_t)s2 * F0))[q];
                float4 r3 = ((const float4*)(xs + (size_t)s3 * F0))[q];
                acc.x += (r0.x + r1.x) + (r2.x + r3.x);
                acc.y += (r0.y + r1.y) + (r2.y + r3.y);
                acc.z += (r0.z + r1.z) + (r2.z + r3.z);
                acc.w += (r0.w + r1.w) + (r2.w + r3.w);
            }
        }
        for (; p < npf; p++) {
            int s0 = __shfl(sidx, 2 * p + half, 64);
            if (act) {
                float4 r0 = ((const float4*)(xs + (size_t)s0 * F0))[q];
                acc.x += r0.x; acc.y += r0.y; acc.z += r0.z; acc.w += r0.w;
            }
        }
        if (cnt & 1) {
            int sl = __shfl(sidx, cnt - 1, 64);
            if (half == 0 && act) {
                float4 r = ((const float4*)(xs + (size_t)sl * F0))[q];
                acc.x += r.x; acc.y += r.y; acc.z += r.z; acc.w += r.w;
            }
        }
    }
    float ox = __shfl_down(acc.x, 32, 64);
    float oy = __shfl_down(acc.y, 32, 64);
    float oz = __shfl_down(acc.z, 32, 64);
    float ow = __shfl_down(acc.w, 32, 64);
    if (half == 0) {
        float4 r = {0.f, 0.f, 0.f, 0.f};
        if (act) {
            r.x = dv * (acc.x + ox);
            r.y = dv * (acc.y + oy);
            r.z = dv * (acc.z + oz);
            r.w = dv * (acc.w + ow);
        }
        f16x4 hh, ll;
        hh[0] = (_Float16)r.x; ll[0] = (_Float16)(r.x - (float)hh[0]);
        hh[1] = (_Float16)r.y; ll[1] = (_Float16)(r.y - (float)hh[1]);
        hh[2] = (_Float16)r.z; ll[2] = (_Float16)(r.z - (float)hh[2]);
        hh[3] = (_Float16)r.w; ll[3] = (_Float16)(r.w - (float)hh[3]);
        *(f16x4*)(aggh + (size_t)v * 128 + 4 * q) = hh;
        *(f16x4*)(aggl + (size_t)v * 128 + 4 * q) = ll;
    }
}

// ---------------- fused GEMM1+GEMM2 (split-fp16 MFMA), r21 exact ----------
// 8 waves (512 thr), M-tile 128, grid 391. Stage 1 direct-global operands,
// stage 2 two 128-col halves through LDS ([128][136] h/l = 68 KB), row-major
// pre-scaled h2 epilogue. Measured 62.3-62.8 us (r21). No setprio (r22
// bundle ambiguous; T5 record in barrier-synced GEMM is null-to-negative).
__global__ __launch_bounds__(512) void gemm12_fused(
        const _Float16* __restrict__ Ah, const _Float16* __restrict__ Al,
        const _Float16* __restrict__ W1h, const _Float16* __restrict__ W1l,
        const _Float16* __restrict__ W2h, const _Float16* __restrict__ W2l,
        const float* __restrict__ b1, const float* __restrict__ dinv,
        float* __restrict__ C, int n) {
    __shared__ _Float16 sAh[128][136], sAl[128][136];   // 68 KB
    int tid = threadIdx.x, lane = tid & 63, wave = tid >> 6;
    int wm = wave >> 2, wn = wave & 3;
    int r0 = blockIdx.x * 128;
    int lr = lane & 15, kg = lane >> 4, ks8 = kg * 8;

    // ---- stage 1 ----
    f32x4 acc1[4][4] = {};
    int arow[4];
#pragma unroll
    for (int i = 0; i < 4; ++i) arow[i] = min(r0 + wm * 64 + i * 16 + lr, n - 1);

#pragma unroll
    for (int k0 = 0; k0 < 128; k0 += 32) {
        f16x8 a_h[4], a_l[4], b_h[4], b_l[4];
#pragma unroll
        for (int i = 0; i < 4; ++i) {
            a_h[i] = *(const f16x8*)(Ah + (size_t)arow[i] * 128 + k0 + ks8);
            a_l[i] = *(const f16x8*)(Al + (size_t)arow[i] * 128 + k0 + ks8);
        }
#pragma unroll
        for (int j = 0; j < 4; ++j) {
            int col = wn * 64 + j * 16 + lr;
            b_h[j] = *(const f16x8*)(W1h + (size_t)col * 128 + k0 + ks8);
            b_l[j] = *(const f16x8*)(W1l + (size_t)col * 128 + k0 + ks8);
        }
#pragma unroll
        for (int i = 0; i < 4; ++i)
#pragma unroll
            for (int j = 0; j < 4; ++j) {
                acc1[i][j] = __builtin_amdgcn_mfma_f32_16x16x32_f16(a_l[i], b_h[j], acc1[i][j], 0, 0, 0);
                acc1[i][j] = __builtin_amdgcn_mfma_f32_16x16x32_f16(a_h[i], b_l[j], acc1[i][j], 0, 0, 0);
                acc1[i][j] = __builtin_amdgcn_mfma_f32_16x16x32_f16(a_h[i], b_h[j], acc1[i][j], 0, 0, 0);
            }
    }
    // bias + relu
#pragma unroll
    for (int j = 0; j < 4; ++j) {
        float bv = b1[wn * 64 + j * 16 + lr];
#pragma unroll
        for (int i = 0; i < 4; ++i)
#pragma unroll
            for (int r = 0; r < 4; ++r)
                acc1[i][j][r] = fmaxf(acc1[i][j][r] + bv, 0.f);
    }

    // ---- stage 2: two 128-mid-col halves through LDS ----
    f32x4 acc2[4][2] = {};
#pragma unroll
    for (int half = 0; half < 2; ++half) {
        if (half) __syncthreads();          // all reads of prev half done
        if ((wn >> 1) == half) {
            int cb = (wn & 1) * 64;
#pragma unroll
            for (int i = 0; i < 4; ++i)
#pragma unroll
                for (int j = 0; j < 4; ++j)
#pragma unroll
                    for (int r = 0; r < 4; ++r) {
                        int row = wm * 64 + i * 16 + kg * 4 + r;
                        int col = cb + j * 16 + lr;
                        float v = acc1[i][j][r];
                        _Float16 h = (_Float16)v;
                        sAh[row][col] = h;
                        sAl[row][col] = (_Float16)(v - (float)h);
                    }
        }
        __syncthreads();
#pragma unroll
        for (int k0 = 0; k0 < 128; k0 += 32) {
            f16x8 a_h[4], a_l[4], b_h[2], b_l[2];
#pragma unroll
            for (int i = 0; i < 4; ++i) {
                a_h[i] = *(const f16x8*)&sAh[wm * 64 + i * 16 + lr][k0 + ks8];
                a_l[i] = *(const f16x8*)&sAl[wm * 64 + i * 16 + lr][k0 + ks8];
            }
#pragma unroll
            for (int j = 0; j < 2; ++j) {
                int col = wn * 32 + j * 16 + lr;
                int kk = half * 128 + k0 + ks8;
                b_h[j] = *(const f16x8*)(W2h + (size_t)col * 256 + kk);
                b_l[j] = *(const f16x8*)(W2l + (size_t)col * 256 + kk);
            }
#pragma unroll
            for (int i = 0; i < 4; ++i)
#pragma unroll
                for (int j = 0; j < 2; ++j) {
                    acc2[i][j] = __builtin_amdgcn_mfma_f32_16x16x32_f16(a_l[i], b_h[j], acc2[i][j], 0, 0, 0);
                    acc2[i][j] = __builtin_amdgcn_mfma_f32_16x16x32_f16(a_h[i], b_l[j], acc2[i][j], 0, 0, 0);
                    acc2[i][j] = __builtin_amdgcn_mfma_f32_16x16x32_f16(a_h[i], b_h[j], acc2[i][j], 0, 0, 0);
                }
        }
    }

    // ---- epilogue: dinv scale, ROW-MAJOR h2 write ----
#pragma unroll
    for (int i = 0; i < 4; ++i)
#pragma unroll
        for (int r = 0; r < 4; ++r) {
            int gr = r0 + wm * 64 + i * 16 + kg * 4 + r;
            if (gr < n) {
                float d = dinv[gr];
#pragma unroll
                for (int j = 0; j < 2; ++j) {
                    int col = wn * 32 + j * 16 + lr;
                    C[(size_t)gr * F2 + col] = acc2[i][j][r] * d;
                }
            }
        }
}

// ---------------- layer-2 fused pull (r10 unchunked) ----------------
__global__ __launch_bounds__(256) void pull_f128_fused(
        const float* __restrict__ h2s, const int* __restrict__ rowptr,
        const int* __restrict__ csr, const float* __restrict__ dinv,
        const float* __restrict__ b2, const float* __restrict__ Wfc,
        const float* __restrict__ bfc, float* __restrict__ out, int n) {
    int wave = threadIdx.x >> 6, lane = threadIdx.x & 63;
    int v = blockIdx.x * 4 + wave;
    if (v >= n) return;
    int beg = rowptr[v], end = rowptr[v + 1];
    float dv = dinv[v];
    int half = lane >> 5, q = lane & 31;
    float4 acc = {0.f, 0.f, 0.f, 0.f};
    if (half == 0) acc = ((const float4*)(h2s + (size_t)v * F2))[q];  // self

    for (int base = beg; base < end; base += 64) {
        int cnt = min(64, end - base);
        int sidx = (lane < cnt) ? csr[base + lane] : 0;
        int npf = cnt >> 1;
        int p = 0;
        for (; p + 4 <= npf; p += 4) {
            int s0 = __shfl(sidx, 2 * p + half, 64);
            int s1 = __shfl(sidx, 2 * p + 2 + half, 64);
            int s2 = __shfl(sidx, 2 * p + 4 + half, 64);
            int s3 = __shfl(sidx, 2 * p + 6 + half, 64);
            float4 r0 = ((const float4*)(h2s + (size_t)s0 * F2))[q];
            float4 r1 = ((const float4*)(h2s + (size_t)s1 * F2))[q];
            float4 r2 = ((const float4*)(h2s + (size_t)s2 * F2))[q];
            float4 r3 = ((const float4*)(h2s + (size_t)s3 * F2))[q];
            acc.x += (r0.x + r1.x) + (r2.x + r3.x);
            acc.y += (r0.y + r1.y) + (r2.y + r3.y);
            acc.z += (r0.z + r1.z) + (r2.z + r3.z);
            acc.w += (r0.w + r1.w) + (r2.w + r3.w);
        }
        for (; p < npf; p++) {
            int s0 = __shfl(sidx, 2 * p + half, 64);
            float4 r0 = ((const float4*)(h2s + (size_t)s0 * F2))[q];
            acc.x += r0.x; acc.y += r0.y; acc.z += r0.z; acc.w += r0.w;
        }
        if (cnt & 1) {
            int sl = __shfl(sidx, cnt - 1, 64);
            if (half == 0) {
                float4 r = ((const float4*)(h2s + (size_t)sl * F2))[q];
                acc.x += r.x; acc.y += r.y; acc.z += r.z; acc.w += r.w;
            }
        }
    }
    float ox = __shfl_down(acc.x, 32, 64);
    float oy = __shfl_down(acc.y, 32, 64);
    float oz = __shfl_down(acc.z, 32, 64);
    float ow = __shfl_down(acc.w, 32, 64);
    if (half == 0) {
        float4 b2v = ((const float4*)b2)[q];
        float4 wv = ((const float4*)Wfc)[q];
        float t0 = dv * (acc.x + ox);
        float t1 = dv * (acc.y + oy);
        float t2 = dv * (acc.z + oz);
        float t3 = dv * (acc.w + ow);
        float part = fmaxf(t0 + b2v.x, 0.f) * wv.x + fmaxf(t1 + b2v.y, 0.f) * wv.y +
                     fmaxf(t2 + b2v.z, 0.f) * wv.z + fmaxf(t3 + b2v.w, 0.f) * wv.w;
        part += __shfl_down(part, 16, 64);
        part += __shfl_down(part, 8, 64);
        part += __shfl_down(part, 4, 64);
        part += __shfl_down(part, 2, 64);
        part += __shfl_down(part, 1, 64);
        if (lane == 0) out[v] = part + bfc[0];
    }
}

// ---------------- launch ----------------

extern "C" void kernel_launch(void* const* d_in, const int* in_sizes, int n_in,
                              void* d_out, int out_size, void* d_ws, size_t ws_size,
                              hipStream_t stream) {
    const float* x   = (const float*)d_in[0];
    const int*   ei  = (const int*)d_in[1];
    const float* W1  = (const float*)d_in[2];
    const float* b1  = (const float*)d_in[3];
    const float* W2  = (const float*)d_in[4];
    const float* b2  = (const float*)d_in[5];
    const float* Wfc = (const float*)d_in[6];
    const float* bfc = (const float*)d_in[7];
    float* out = (float*)d_out;

    const int n = in_sizes[0] / F0;   // 50000
    const int e = in_sizes[1] / 2;    // 800000
    const int* src = ei;
    const int* dst = ei + e;

    // workspace (byte offsets, 256-B aligned regions, lifetime unions)
    char* wsb = (char*)d_ws;
    size_t off = 0;
    auto alloc = [&](size_t bytes) -> void* {
        off = (off + 255) & ~(size_t)255;
        void* r = wsb + off;
        off += bytes;
        return r;
    };
    int* deg    = (int*)alloc((size_t)n * 4);
    int* excl   = (int*)alloc((size_t)n * 4);
    int* bsum   = (int*)alloc(1024);
    int* rowptr = (int*)alloc((size_t)(n + 1) * 4);
    int* cursor = (int*)alloc((size_t)n * 4);
    int* csr    = (int*)alloc((size_t)e * 4);
    float* dinv = (float*)alloc((size_t)n * 4);
    _Float16* W1h = (_Float16*)alloc(256 * 128 * 2);
    _Float16* W1l = (_Float16*)alloc(256 * 128 * 2);
    _Float16* W2h = (_Float16*)alloc(128 * 256 * 2);
    _Float16* W2l = (_Float16*)alloc(128 * 256 * 2);
    // bufA: xs (n*100 f32) THEN h2 (n*128 f32); xs dead before gemm12 writes
    char* bufA = (char*)alloc((size_t)n * 128 * 4);
    float* xs = (float*)bufA;
    float* h2 = (float*)bufA;
    // aggX h/l: alive from pull_f100 through gemm12 — own region
    _Float16* aggh = (_Float16*)alloc((size_t)n * 128 * 2);
    _Float16* aggl = (_Float16*)alloc((size_t)n * 128 * 2);

    const int B = 256;
    const int nb = (n + B - 1) / B;

    hipMemsetAsync(deg, 0, (size_t)n * 4, stream);
    deg_count_i<<<(e + B - 1) / B, B, 0, stream>>>(dst, deg, e);
    scan1_scale<<<nb, B, 0, stream>>>(deg, excl, bsum, dinv,
                                      (const float4*)x, (float4*)xs, n);
    wprep<<<256, 256, 0, stream>>>(W1, W2, W1h, W1l, W2h, W2l);
    scan2<<<1, B, 0, stream>>>(bsum, nb, rowptr, n);
    scan3<<<nb, B, 0, stream>>>(excl, bsum, rowptr, cursor, n);
    csr_fill<<<(e + B - 1) / B, B, 0, stream>>>(src, dst, cursor, csr, e);

    // layer 1: pull-aggregate xs -> split-fp16 aggX
    pull_f100<<<(n + 3) / 4, 256, 0, stream>>>(xs, rowptr, csr, dinv, aggh, aggl, n);
    // fused GEMM1+GEMM2 -> row-major pre-scaled h2 (overwrites dead xs region)
    gemm12_fused<<<(n + 127) / 128, 512, 0, stream>>>(aggh, aggl, W1h, W1l,
                                                      W2h, W2l, b1, dinv, h2, n);
    // layer-2 fused pull + bias + relu + FC
    pull_f128_fused<<<(n + 3) / 4, 256, 0, stream>>>(h2, rowptr, csr, dinv,
                                                     b2, Wfc, bfc, out, n);
}

// Round 15
// 335.281 us; speedup vs baseline: 1.0356x; 1.0252x over previous
//
#include <hip/hip_runtime.h>
#include <hip/hip_bf16.h>

// GCN: out = relu(gcnconv(relu(gcnconv(x,W1,b1)), W2, b2)) @ Wfc + bfc
// N=50000, E=800000, F0=100, F1=256, F2=128.
// Round 24: revert to r21 EXACT (336.6 us, session best). r23 isolated
// scan1_scale as a -7 us regression: fusing the 40 MB xs scale into scan1's
// 196-block grid (<1 block/CU) strangled a memory-bound copy that scale_x
// spreads over 4883 blocks. All levers now bracketed: gathers at the
// random-line ceiling (r10-r14), gemm12 at the VGPR-vs-waves optimum
// (r16-r20), CSR scatters atomic-bound at max parallelism (r22-r23),
// fusion wins (a1 elimination, pre-scaling, row-major h2, unchunked pull)
// already in. Numerics: split-fp16 3-term MFMA (ah*bh+ah*bl+al*bh,
// fp32 acc), absmax 4.9e-4.

#define F0 100
#define F1 256
#define F2 128

typedef _Float16 f16x4 __attribute__((ext_vector_type(4)));
typedef _Float16 f16x8 __attribute__((ext_vector_type(8)));
typedef float f32x4 __attribute__((ext_vector_type(4)));

// ---------------- CSR construction ----------------

__global__ void deg_count_i(const int* __restrict__ dst, int* deg, int e) {
    int i = blockIdx.x * blockDim.x + threadIdx.x;
    if (i < e) atomicAdd(deg + dst[i], 1);
}

__global__ __launch_bounds__(256) void scan1(const int* __restrict__ deg,
                                             int* __restrict__ excl,
                                             int* __restrict__ bsum,
                                             float* __restrict__ dinv, int n) {
    __shared__ int wsum[4];
    int i = blockIdx.x * 256 + threadIdx.x;
    int lane = threadIdx.x & 63, wid = threadIdx.x >> 6;
    int v = (i < n) ? deg[i] : 0;
    if (i < n) dinv[i] = rsqrtf((float)(v + 1));
    int s = v;
#pragma unroll
    for (int off = 1; off < 64; off <<= 1) {
        int t = __shfl_up(s, off, 64);
        if (lane >= off) s += t;
    }
    if (lane == 63) wsum[wid] = s;
    __syncthreads();
    int add = 0;
    for (int w = 0; w < wid; w++) add += wsum[w];
    if (i < n) excl[i] = add + s - v;
    if (threadIdx.x == 255) bsum[blockIdx.x] = add + s;
}

__global__ __launch_bounds__(256) void scan2(int* __restrict__ bsum, int nb,
                                             int* __restrict__ rowptr, int n) {
    __shared__ int wsum[4];
    int lane = threadIdx.x & 63, wid = threadIdx.x >> 6;
    int v = (threadIdx.x < nb) ? bsum[threadIdx.x] : 0;
    int s = v;
#pragma unroll
    for (int off = 1; off < 64; off <<= 1) {
        int t = __shfl_up(s, off, 64);
        if (lane >= off) s += t;
    }
    if (lane == 63) wsum[wid] = s;
    __syncthreads();
    int add = 0;
    for (int w = 0; w < wid; w++) add += wsum[w];
    if (threadIdx.x < nb) bsum[threadIdx.x] = add + s - v;
    if (threadIdx.x == 255) rowptr[n] = add + s;
}

__global__ void scan3(const int* __restrict__ excl, const int* __restrict__ bsum,
                      int* __restrict__ rowptr, int* __restrict__ cursor, int n) {
    int i = blockIdx.x * 256 + threadIdx.x;
    if (i < n) {
        int r = excl[i] + bsum[blockIdx.x];
        rowptr[i] = r;
        cursor[i] = r;
    }
}

__global__ void csr_fill(const int* __restrict__ src, const int* __restrict__ dst,
                         int* cursor, int* __restrict__ csr, int e) {
    int i = blockIdx.x * blockDim.x + threadIdx.x;
    if (i < e) {
        int pos = atomicAdd(cursor + dst[i], 1);
        csr[pos] = src[i];
    }
}

// xs = dinv[row] * x
__global__ void scale_x(const float4* __restrict__ x4,
                        const float* __restrict__ dinv,
                        float4* __restrict__ xs4, int n25) {
    int i = blockIdx.x * blockDim.x + threadIdx.x;
    if (i < n25) {
        float d = dinv[i / 25];
        float4 v = x4[i];
        v.x *= d; v.y *= d; v.z *= d; v.w *= d;
        xs4[i] = v;
    }
}

// W1t_h/l: [256][128] = W1^T zero-padded K 100->128, split fp16 hi/lo.
// W2t_h/l: [128][256] = W2^T, split fp16 hi/lo.
__global__ void wprep(const float* __restrict__ W1, const float* __restrict__ W2,
                      _Float16* __restrict__ W1h, _Float16* __restrict__ W1l,
                      _Float16* __restrict__ W2h, _Float16* __restrict__ W2l) {
    int i = blockIdx.x * 256 + threadIdx.x;
    if (i < 256 * 128) {
        int c = i >> 7, k = i & 127;
        float v = (k < F0) ? W1[(size_t)k * F1 + c] : 0.f;
        _Float16 h = (_Float16)v;
        W1h[i] = h;
        W1l[i] = (_Float16)(v - (float)h);
    } else if (i < 256 * 128 + 128 * 256) {
        int j = i - 256 * 128;
        int c = j >> 8, k = j & 255;
        float v = W2[(size_t)k * F2 + c];
        _Float16 h = (_Float16)v;
        W2h[j] = h;
        W2l[j] = (_Float16)(v - (float)h);
    }
}

// ---------------- layer-1 pull aggregation -> split-fp16 aggX -------------

__global__ __launch_bounds__(256) void pull_f100(
        const float* __restrict__ xs, const int* __restrict__ rowptr,
        const int* __restrict__ csr, const float* __restrict__ dinv,
        _Float16* __restrict__ aggh, _Float16* __restrict__ aggl, int n) {
    int wave = threadIdx.x >> 6, lane = threadIdx.x & 63;
    int v = blockIdx.x * 4 + wave;
    if (v >= n) return;
    int beg = rowptr[v], end = rowptr[v + 1];
    float dv = dinv[v];
    int half = lane >> 5, q = lane & 31;
    bool act = q < 25;
    float4 acc = {0.f, 0.f, 0.f, 0.f};
    if (half == 0 && act) acc = ((const float4*)(xs + (size_t)v * F0))[q];  // self

    for (int base = beg; base < end; base += 64) {
        int cnt = min(64, end - base);
        int sidx = (lane < cnt) ? csr[base + lane] : 0;
        int npf = cnt >> 1;
        int p = 0;
        for (; p + 4 <= npf; p += 4) {
            int s0 = __shfl(sidx, 2 * p + half, 64);
            int s1 = __shfl(sidx, 2 * p + 2 + half, 64);
            int s2 = __shfl(sidx, 2 * p + 4 + half, 64);
            int s3 = __shfl(sidx, 2 * p + 6 + half, 64);
            if (act) {
                float4 r0 = ((const float4*)(xs + (size_t)s0 * F0))[q];
                float4 r1 = ((const float4*)(xs + (size_t)s1 * F0))[q];
                float4 r2 = ((const float4*)(xs + (size_t)s2 * F0))[q];
                float4 r3 = ((const float4*)(xs + (size_t)s3 * F0))[q];
                acc.x += (r0.x + r1.x) + (r2.x + r3.x);
                acc.y += (r0.y + r1.y) + (r2.y + r3.y);
                acc.z += (r0.z + r1.z) + (r2.z + r3.z);
                acc.w += (r0.w + r1.w) + (r2.w + r3.w);
            }
        }
        for (; p < npf; p++) {
            int s0 = __shfl(sidx, 2 * p + half, 64);
            if (act) {
                float4 r0 = ((const float4*)(xs + (size_t)s0 * F0))[q];
                acc.x += r0.x; acc.y += r0.y; acc.z += r0.z; acc.w += r0.w;
            }
        }
        if (cnt & 1) {
            int sl = __shfl(sidx, cnt - 1, 64);
            if (half == 0 && act) {
                float4 r = ((const float4*)(xs + (size_t)sl * F0))[q];
                acc.x += r.x; acc.y += r.y; acc.z += r.z; acc.w += r.w;
            }
        }
    }
    float ox = __shfl_down(acc.x, 32, 64);
    float oy = __shfl_down(acc.y, 32, 64);
    float oz = __shfl_down(acc.z, 32, 64);
    float ow = __shfl_down(acc.w, 32, 64);
    if (half == 0) {
        float4 r = {0.f, 0.f, 0.f, 0.f};
        if (act) {
            r.x = dv * (acc.x + ox);
            r.y = dv * (acc.y + oy);
            r.z = dv * (acc.z + oz);
            r.w = dv * (acc.w + ow);
        }
        f16x4 hh, ll;
        hh[0] = (_Float16)r.x; ll[0] = (_Float16)(r.x - (float)hh[0]);
        hh[1] = (_Float16)r.y; ll[1] = (_Float16)(r.y - (float)hh[1]);
        hh[2] = (_Float16)r.z; ll[2] = (_Float16)(r.z - (float)hh[2]);
        hh[3] = (_Float16)r.w; ll[3] = (_Float16)(r.w - (float)hh[3]);
        *(f16x4*)(aggh + (size_t)v * 128 + 4 * q) = hh;
        *(f16x4*)(aggl + (size_t)v * 128 + 4 * q) = ll;
    }
}

// ---------------- fused GEMM1+GEMM2 (split-fp16 MFMA), r16 structure ------
// 8 waves (512 thr), M-tile 128, grid 391. Stage 1: acc1[4][4], operands
// direct from global (A coalesced, W1t L2-resident). Stage 2: TWO 128-col
// halves through LDS ([128][136] h/l = 68 KB). Row-major pre-scaled h2
// epilogue. Measured 62.3-62.8 us (r21/r23).
__global__ __launch_bounds__(512) void gemm12_fused(
        const _Float16* __restrict__ Ah, const _Float16* __restrict__ Al,
        const _Float16* __restrict__ W1h, const _Float16* __restrict__ W1l,
        const _Float16* __restrict__ W2h, const _Float16* __restrict__ W2l,
        const float* __restrict__ b1, const float* __restrict__ dinv,
        float* __restrict__ C, int n) {
    __shared__ _Float16 sAh[128][136], sAl[128][136];   // 68 KB
    int tid = threadIdx.x, lane = tid & 63, wave = tid >> 6;
    int wm = wave >> 2, wn = wave & 3;
    int r0 = blockIdx.x * 128;
    int lr = lane & 15, kg = lane >> 4, ks8 = kg * 8;

    // ---- stage 1 ----
    f32x4 acc1[4][4] = {};
    int arow[4];
#pragma unroll
    for (int i = 0; i < 4; ++i) arow[i] = min(r0 + wm * 64 + i * 16 + lr, n - 1);

#pragma unroll
    for (int k0 = 0; k0 < 128; k0 += 32) {
        f16x8 a_h[4], a_l[4], b_h[4], b_l[4];
#pragma unroll
        for (int i = 0; i < 4; ++i) {
            a_h[i] = *(const f16x8*)(Ah + (size_t)arow[i] * 128 + k0 + ks8);
            a_l[i] = *(const f16x8*)(Al + (size_t)arow[i] * 128 + k0 + ks8);
        }
#pragma unroll
        for (int j = 0; j < 4; ++j) {
            int col = wn * 64 + j * 16 + lr;
            b_h[j] = *(const f16x8*)(W1h + (size_t)col * 128 + k0 + ks8);
            b_l[j] = *(const f16x8*)(W1l + (size_t)col * 128 + k0 + ks8);
        }
#pragma unroll
        for (int i = 0; i < 4; ++i)
#pragma unroll
            for (int j = 0; j < 4; ++j) {
                acc1[i][j] = __builtin_amdgcn_mfma_f32_16x16x32_f16(a_l[i], b_h[j], acc1[i][j], 0, 0, 0);
                acc1[i][j] = __builtin_amdgcn_mfma_f32_16x16x32_f16(a_h[i], b_l[j], acc1[i][j], 0, 0, 0);
                acc1[i][j] = __builtin_amdgcn_mfma_f32_16x16x32_f16(a_h[i], b_h[j], acc1[i][j], 0, 0, 0);
            }
    }
    // bias + relu
#pragma unroll
    for (int j = 0; j < 4; ++j) {
        float bv = b1[wn * 64 + j * 16 + lr];
#pragma unroll
        for (int i = 0; i < 4; ++i)
#pragma unroll
            for (int r = 0; r < 4; ++r)
                acc1[i][j][r] = fmaxf(acc1[i][j][r] + bv, 0.f);
    }

    // ---- stage 2: two 128-mid-col halves through LDS ----
    f32x4 acc2[4][2] = {};
#pragma unroll
    for (int half = 0; half < 2; ++half) {
        if (half) __syncthreads();          // all reads of prev half done
        if ((wn >> 1) == half) {
            int cb = (wn & 1) * 64;
#pragma unroll
            for (int i = 0; i < 4; ++i)
#pragma unroll
                for (int j = 0; j < 4; ++j)
#pragma unroll
                    for (int r = 0; r < 4; ++r) {
                        int row = wm * 64 + i * 16 + kg * 4 + r;
                        int col = cb + j * 16 + lr;
                        float v = acc1[i][j][r];
                        _Float16 h = (_Float16)v;
                        sAh[row][col] = h;
                        sAl[row][col] = (_Float16)(v - (float)h);
                    }
        }
        __syncthreads();
#pragma unroll
        for (int k0 = 0; k0 < 128; k0 += 32) {
            f16x8 a_h[4], a_l[4], b_h[2], b_l[2];
#pragma unroll
            for (int i = 0; i < 4; ++i) {
                a_h[i] = *(const f16x8*)&sAh[wm * 64 + i * 16 + lr][k0 + ks8];
                a_l[i] = *(const f16x8*)&sAl[wm * 64 + i * 16 + lr][k0 + ks8];
            }
#pragma unroll
            for (int j = 0; j < 2; ++j) {
                int col = wn * 32 + j * 16 + lr;
                int kk = half * 128 + k0 + ks8;
                b_h[j] = *(const f16x8*)(W2h + (size_t)col * 256 + kk);
                b_l[j] = *(const f16x8*)(W2l + (size_t)col * 256 + kk);
            }
#pragma unroll
            for (int i = 0; i < 4; ++i)
#pragma unroll
                for (int j = 0; j < 2; ++j) {
                    acc2[i][j] = __builtin_amdgcn_mfma_f32_16x16x32_f16(a_l[i], b_h[j], acc2[i][j], 0, 0, 0);
                    acc2[i][j] = __builtin_amdgcn_mfma_f32_16x16x32_f16(a_h[i], b_l[j], acc2[i][j], 0, 0, 0);
                    acc2[i][j] = __builtin_amdgcn_mfma_f32_16x16x32_f16(a_h[i], b_h[j], acc2[i][j], 0, 0, 0);
                }
        }
    }

    // ---- epilogue: dinv scale, ROW-MAJOR h2 write ----
#pragma unroll
    for (int i = 0; i < 4; ++i)
#pragma unroll
        for (int r = 0; r < 4; ++r) {
            int gr = r0 + wm * 64 + i * 16 + kg * 4 + r;
            if (gr < n) {
                float d = dinv[gr];
#pragma unroll
                for (int j = 0; j < 2; ++j) {
                    int col = wn * 32 + j * 16 + lr;
                    C[(size_t)gr * F2 + col] = acc2[i][j][r] * d;
                }
            }
        }
}

// ---------------- layer-2 fused pull (r10 unchunked) ----------------
__global__ __launch_bounds__(256) void pull_f128_fused(
        const float* __restrict__ h2s, const int* __restrict__ rowptr,
        const int* __restrict__ csr, const float* __restrict__ dinv,
        const float* __restrict__ b2, const float* __restrict__ Wfc,
        const float* __restrict__ bfc, float* __restrict__ out, int n) {
    int wave = threadIdx.x >> 6, lane = threadIdx.x & 63;
    int v = blockIdx.x * 4 + wave;
    if (v >= n) return;
    int beg = rowptr[v], end = rowptr[v + 1];
    float dv = dinv[v];
    int half = lane >> 5, q = lane & 31;
    float4 acc = {0.f, 0.f, 0.f, 0.f};
    if (half == 0) acc = ((const float4*)(h2s + (size_t)v * F2))[q];  // self

    for (int base = beg; base < end; base += 64) {
        int cnt = min(64, end - base);
        int sidx = (lane < cnt) ? csr[base + lane] : 0;
        int npf = cnt >> 1;
        int p = 0;
        for (; p + 4 <= npf; p += 4) {
            int s0 = __shfl(sidx, 2 * p + half, 64);
            int s1 = __shfl(sidx, 2 * p + 2 + half, 64);
            int s2 = __shfl(sidx, 2 * p + 4 + half, 64);
            int s3 = __shfl(sidx, 2 * p + 6 + half, 64);
            float4 r0 = ((const float4*)(h2s + (size_t)s0 * F2))[q];
            float4 r1 = ((const float4*)(h2s + (size_t)s1 * F2))[q];
            float4 r2 = ((const float4*)(h2s + (size_t)s2 * F2))[q];
            float4 r3 = ((const float4*)(h2s + (size_t)s3 * F2))[q];
            acc.x += (r0.x + r1.x) + (r2.x + r3.x);
            acc.y += (r0.y + r1.y) + (r2.y + r3.y);
            acc.z += (r0.z + r1.z) + (r2.z + r3.z);
            acc.w += (r0.w + r1.w) + (r2.w + r3.w);
        }
        for (; p < npf; p++) {
            int s0 = __shfl(sidx, 2 * p + half, 64);
            float4 r0 = ((const float4*)(h2s + (size_t)s0 * F2))[q];
            acc.x += r0.x; acc.y += r0.y; acc.z += r0.z; acc.w += r0.w;
        }
        if (cnt & 1) {
            int sl = __shfl(sidx, cnt - 1, 64);
            if (half == 0) {
                float4 r = ((const float4*)(h2s + (size_t)sl * F2))[q];
                acc.x += r.x; acc.y += r.y; acc.z += r.z; acc.w += r.w;
            }
        }
    }
    float ox = __shfl_down(acc.x, 32, 64);
    float oy = __shfl_down(acc.y, 32, 64);
    float oz = __shfl_down(acc.z, 32, 64);
    float ow = __shfl_down(acc.w, 32, 64);
    if (half == 0) {
        float4 b2v = ((const float4*)b2)[q];
        float4 wv = ((const float4*)Wfc)[q];
        float t0 = dv * (acc.x + ox);
        float t1 = dv * (acc.y + oy);
        float t2 = dv * (acc.z + oz);
        float t3 = dv * (acc.w + ow);
        float part = fmaxf(t0 + b2v.x, 0.f) * wv.x + fmaxf(t1 + b2v.y, 0.f) * wv.y +
                     fmaxf(t2 + b2v.z, 0.f) * wv.z + fmaxf(t3 + b2v.w, 0.f) * wv.w;
        part += __shfl_down(part, 16, 64);
        part += __shfl_down(part, 8, 64);
        part += __shfl_down(part, 4, 64);
        part += __shfl_down(part, 2, 64);
        part += __shfl_down(part, 1, 64);
        if (lane == 0) out[v] = part + bfc[0];
    }
}

// ---------------- launch ----------------

extern "C" void kernel_launch(void* const* d_in, const int* in_sizes, int n_in,
                              void* d_out, int out_size, void* d_ws, size_t ws_size,
                              hipStream_t stream) {
    const float* x   = (const float*)d_in[0];
    const int*   ei  = (const int*)d_in[1];
    const float* W1  = (const float*)d_in[2];
    const float* b1  = (const float*)d_in[3];
    const float* W2  = (const float*)d_in[4];
    const float* b2  = (const float*)d_in[5];
    const float* Wfc = (const float*)d_in[6];
    const float* bfc = (const float*)d_in[7];
    float* out = (float*)d_out;

    const int n = in_sizes[0] / F0;   // 50000
    const int e = in_sizes[1] / 2;    // 800000
    const int* src = ei;
    const int* dst = ei + e;

    // workspace (byte offsets, 256-B aligned regions, lifetime unions)
    char* wsb = (char*)d_ws;
    size_t off = 0;
    auto alloc = [&](size_t bytes) -> void* {
        off = (off + 255) & ~(size_t)255;
        void* r = wsb + off;
        off += bytes;
        return r;
    };
    int* deg    = (int*)alloc((size_t)n * 4);
    int* excl   = (int*)alloc((size_t)n * 4);
    int* bsum   = (int*)alloc(1024);
    int* rowptr = (int*)alloc((size_t)(n + 1) * 4);
    int* cursor = (int*)alloc((size_t)n * 4);
    int* csr    = (int*)alloc((size_t)e * 4);
    float* dinv = (float*)alloc((size_t)n * 4);
    _Float16* W1h = (_Float16*)alloc(256 * 128 * 2);
    _Float16* W1l = (_Float16*)alloc(256 * 128 * 2);
    _Float16* W2h = (_Float16*)alloc(128 * 256 * 2);
    _Float16* W2l = (_Float16*)alloc(128 * 256 * 2);
    // bufA: xs (n*100 f32) THEN h2 (n*128 f32); xs dead before gemm12 writes
    char* bufA = (char*)alloc((size_t)n * 128 * 4);
    float* xs = (float*)bufA;
    float* h2 = (float*)bufA;
    // aggX h/l: alive from pull_f100 through gemm12 — own region
    _Float16* aggh = (_Float16*)alloc((size_t)n * 128 * 2);
    _Float16* aggl = (_Float16*)alloc((size_t)n * 128 * 2);

    const int B = 256;
    const int nb = (n + B - 1) / B;

    hipMemsetAsync(deg, 0, (size_t)n * 4, stream);
    deg_count_i<<<(e + B - 1) / B, B, 0, stream>>>(dst, deg, e);
    scan1<<<nb, B, 0, stream>>>(deg, excl, bsum, dinv, n);
    scale_x<<<((n * 25) + B - 1) / B, B, 0, stream>>>(
        (const float4*)x, dinv, (float4*)xs, n * 25);
    wprep<<<256, 256, 0, stream>>>(W1, W2, W1h, W1l, W2h, W2l);
    scan2<<<1, B, 0, stream>>>(bsum, nb, rowptr, n);
    scan3<<<nb, B, 0, stream>>>(excl, bsum, rowptr, cursor, n);
    csr_fill<<<(e + B - 1) / B, B, 0, stream>>>(src, dst, cursor, csr, e);

    // layer 1: pull-aggregate xs -> split-fp16 aggX
    pull_f100<<<(n + 3) / 4, 256, 0, stream>>>(xs, rowptr, csr, dinv, aggh, aggl, n);
    // fused GEMM1+GEMM2 -> row-major pre-scaled h2 (overwrites dead xs region)
    gemm12_fused<<<(n + 127) / 128, 512, 0, stream>>>(aggh, aggl, W1h, W1l,
                                                      W2h, W2l, b1, dinv, h2, n);
    // layer-2 fused pull + bias + relu + FC
    pull_f128_fused<<<(n + 3) / 4, 256, 0, stream>>>(h2, rowptr, csr, dinv,
                                                     b2, Wfc, bfc, out, n);
}